// Round 6
// baseline (462.736 us; speedup 1.0000x reference)
//
#include <hip/hip_runtime.h>
#include <stdint.h>

#define DEV __device__ __forceinline__

typedef __bf16 bf16x8 __attribute__((ext_vector_type(8)));
typedef unsigned short u16x8 __attribute__((ext_vector_type(8)));
typedef float f32x4 __attribute__((ext_vector_type(4)));

// n-dimension padded stride: 992 = 31*32 (row stride 1984 B, exact 128-tiling)
#define NS 992

// ---------- bf16 helpers (RNE) ----------
DEV uint16_t f2bf(float f) {
    union { float f; uint32_t u; } v; v.f = f;
    uint32_t r = v.u + 0x7fffu + ((v.u >> 16) & 1u);
    return (uint16_t)(r >> 16);
}
DEV float bf2f(uint16_t h) {
    union { uint32_t u; float f; } v; v.u = ((uint32_t)h) << 16;
    return v.f;
}
DEV float bflo(uint32_t w) { union { uint32_t u; float f; } v; v.u = w << 16; return v.f; }
DEV float bfhi(uint32_t w) { union { uint32_t u; float f; } v; v.u = w & 0xffff0000u; return v.f; }

#if __has_builtin(__builtin_amdgcn_cvt_pk_bf16_f32)
typedef __bf16 bf16x2 __attribute__((ext_vector_type(2)));
DEV uint32_t pk2bf(float lo, float hi) {
    bf16x2 r = __builtin_amdgcn_cvt_pk_bf16_f32(lo, hi);
    return __builtin_bit_cast(uint32_t, r);
}
#else
DEV uint32_t pk2bf(float lo, float hi) {
    return (uint32_t)f2bf(lo) | ((uint32_t)f2bf(hi) << 16);
}
#endif

// inclusive 32-wide shuffle scan (Hillis-Steele, 5 steps)
DEV float scan32(float v, int lane) {
    #pragma unroll
    for (int d = 1; d < 32; d <<= 1) {
        float o = __shfl_up(v, d, 32);
        if (lane >= d) v += o;
    }
    return v;
}

// window table: w in [0,75) -> r0,r1,c0,c1
DEV void win_idx(int w, int& r0, int& r1, int& c0, int& c1) {
    int i = w / 5 + 1, t = w % 5;
    const int m = 15;
    switch (t) {
        case 0: r0 = m - i; r1 = m + i + 1; c0 = m - i; c1 = m + i + 1; break;
        case 1: r0 = m - i; r1 = m + 1;     c0 = m - i; c1 = m + i + 1; break;
        case 2: r0 = m;     r1 = m + i + 1; c0 = m - i; c1 = m + i + 1; break;
        case 3: r0 = m - i; r1 = m + i + 1; c0 = m - i; c1 = m + 1;     break;
        default:r0 = m - i; r1 = m + i + 1; c0 = m;     c1 = m + i + 1; break;
    }
}

// ---------- async global->LDS, 16B per lane ----------
#if __has_builtin(__builtin_amdgcn_global_load_lds)
DEV void async16(const uint16_t* g, uint16_t* l) {
    __builtin_amdgcn_global_load_lds(
        (const __attribute__((address_space(1))) uint32_t*)g,
        (__attribute__((address_space(3))) uint32_t*)l, 16, 0, 0);
}
#else
DEV void async16(const uint16_t* g, uint16_t* l) {
    *(u16x8*)l = *(const u16x8*)g;
}
#endif

// ---------- transpose + bf16 cast: x (B,512,961) f32 -> xbt (B*992, 512) bf16 ----------
__global__ void k_convert_x(const float* __restrict__ x, uint16_t* __restrict__ xbt) {
    __shared__ float tile[32][33];
    int b = blockIdx.z;
    int n0 = blockIdx.x * 32;
    int c0 = blockIdx.y * 32;
    int tx = threadIdx.x, ty = threadIdx.y;   // 32 x 8
    #pragma unroll
    for (int i = 0; i < 4; ++i) {
        int c = c0 + ty + 8 * i;
        int n = n0 + tx;
        float v = 0.f;
        if (n < 961) v = x[((size_t)b * 512 + c) * 961 + n];
        tile[ty + 8 * i][tx] = v;
    }
    __syncthreads();
    int idx = ty * 32 + tx;          // 0..255
    int c4 = (idx & 7) * 4;          // 0..28
    int nl = idx >> 3;               // 0..31
    int n = n0 + nl;
    ushort4 val;
    val.x = f2bf(tile[c4 + 0][nl]);
    val.y = f2bf(tile[c4 + 1][nl]);
    val.z = f2bf(tile[c4 + 2][nl]);
    val.w = f2bf(tile[c4 + 3][nl]);
    *(ushort4*)&xbt[((size_t)b * NS + n) * 512 + c0 + c4] = val;
}

// merged weight converts: wvkt[j][k] (1024x512 B^T) and wfct[j][k] (512x1024 B^T)
__global__ void k_convert_w(const float* __restrict__ wv, const float* __restrict__ wk,
                            const float* __restrict__ wfc,
                            uint16_t* __restrict__ wvkt, uint16_t* __restrict__ wfct) {
    int idx = blockIdx.x * 256 + threadIdx.x;   // 0 .. 1048575
    if (idx < 524288) {
        int j = idx >> 9, k = idx & 511;
        float v = (j < 512) ? wv[(size_t)k * 512 + j] : wk[(size_t)k * 512 + (j - 512)];
        wvkt[idx] = f2bf(v);
    } else {
        int t = idx - 524288;
        int j = t >> 10, k = t & 1023;
        wfct[t] = f2bf(wfc[(size_t)k * 512 + j]);
    }
}

// ---------- bf16 MFMA GEMM, 128x128 tile, BK=64 (two 32-k panels) ----------
template<int K, int EPI>
__global__ __launch_bounds__(256, 4)
void k_gemm(const uint16_t* __restrict__ A, const uint16_t* __restrict__ Bt,
            uint16_t* __restrict__ out_v, uint16_t* __restrict__ out_k,
            float* __restrict__ out_f,
            float* __restrict__ colsum, float* __restrict__ colsq)
{
    __shared__ __align__(16) uint16_t sbuf[16384];   // 32 KB staging / epi-transpose
    __shared__ float sStat[256];
    uint16_t* sA0 = sbuf;
    uint16_t* sA1 = sbuf + 4096;
    uint16_t* sB0 = sbuf + 8192;
    uint16_t* sB1 = sbuf + 12288;

    const int tid = threadIdx.x;
    const int wave = tid >> 6, lane = tid & 63;
    const int quad = lane >> 4, l16 = lane & 15;
    int m0, j0;
    if constexpr (EPI == 0) {
        int lin = blockIdx.x;            // 62*8*8 = 3968, 496 m-tiles exact
        int xcd = lin & 7, rest = lin >> 3;
        int jb = rest & 7, mhi = rest >> 3;
        m0 = (mhi * 8 + xcd) * 128; j0 = jb * 128;
    } else {
        m0 = blockIdx.y * 128; j0 = blockIdx.x * 128;
    }
    const int wm = wave >> 1, wj = wave & 1;

    const f32x4 fzero = {0.f, 0.f, 0.f, 0.f};
    f32x4 acc[4][4];
    #pragma unroll
    for (int i = 0; i < 4; ++i)
        #pragma unroll
        for (int j = 0; j < 4; ++j) acc[i][j] = fzero;

    const int c0 = tid;
    const int mA0 = c0 >> 2, kq0 = c0 & 3;
    const int c1 = tid + 256;
    const int mA1 = c1 >> 2, kq1 = c1 & 3;

    const int KT = K / 64;
    for (int kt = 0; kt < KT; ++kt) {
        const uint16_t* Ak = A + (size_t)m0 * K + kt * 64;
        const uint16_t* Bk = Bt + (size_t)j0 * K + kt * 64;
        async16(Ak + (size_t)mA0 * K + kq0 * 8,      &sA0[c0 * 8]);
        async16(Ak + (size_t)mA1 * K + kq1 * 8,      &sA0[c1 * 8]);
        async16(Ak + (size_t)mA0 * K + 32 + kq0 * 8, &sA1[c0 * 8]);
        async16(Ak + (size_t)mA1 * K + 32 + kq1 * 8, &sA1[c1 * 8]);
        async16(Bk + (size_t)mA0 * K + kq0 * 8,      &sB0[c0 * 8]);
        async16(Bk + (size_t)mA1 * K + kq1 * 8,      &sB0[c1 * 8]);
        async16(Bk + (size_t)mA0 * K + 32 + kq0 * 8, &sB1[c0 * 8]);
        async16(Bk + (size_t)mA1 * K + 32 + kq1 * 8, &sB1[c1 * 8]);
        __syncthreads();
        #pragma unroll
        for (int p = 0; p < 2; ++p) {
            const uint16_t* pA = p ? sA1 : sA0;
            const uint16_t* pB = p ? sB1 : sB0;
            bf16x8 af[4], bfr[4];
            #pragma unroll
            for (int i = 0; i < 4; ++i) {
                int m = wm * 64 + i * 16 + l16;
                u16x8 r = *(const u16x8*)&pA[m * 32 + quad * 8];
                af[i] = __builtin_bit_cast(bf16x8, r);
            }
            #pragma unroll
            for (int j = 0; j < 4; ++j) {
                int jj = wj * 64 + j * 16 + l16;
                u16x8 r = *(const u16x8*)&pB[jj * 32 + quad * 8];
                bfr[j] = __builtin_bit_cast(bf16x8, r);
            }
            #pragma unroll
            for (int i = 0; i < 4; ++i)
                #pragma unroll
                for (int j = 0; j < 4; ++j)
                    acc[i][j] = __builtin_amdgcn_mfma_f32_16x16x32_bf16(af[i], bfr[j], acc[i][j], 0, 0, 0);
        }
        __syncthreads();
    }

    // ---- column stats (pad rows exactly zero -> unconditional) ----
    sStat[tid] = 0.f;
    __syncthreads();

    #pragma unroll
    for (int j = 0; j < 4; ++j) {
        const int col_local = wj * 64 + j * 16 + l16;
        float ls = 0.f, lq = 0.f;
        #pragma unroll
        for (int i = 0; i < 4; ++i) {
            #pragma unroll
            for (int reg = 0; reg < 4; ++reg) {
                const float val = acc[i][j][reg];
                ls += val; lq += val * val;
                if constexpr (EPI == 1) {
                    const int r = m0 + wm * 64 + i * 16 + quad * 4 + reg;
                    out_f[(size_t)r * 512 + (j0 + col_local)] = val;
                }
            }
        }
        ls += __shfl_xor(ls, 16); lq += __shfl_xor(lq, 16);
        ls += __shfl_xor(ls, 32); lq += __shfl_xor(lq, 32);
        if (quad == 0) {
            atomicAdd(&sStat[col_local], ls);
            atomicAdd(&sStat[128 + col_local], lq);
        }
    }
    __syncthreads();
    if (tid < 128) atomicAdd(&colsum[j0 + tid], sStat[tid]);
    else           atomicAdd(&colsq[j0 + (tid & 127)], sStat[tid]);

    if constexpr (EPI == 0) {
        // ---- LDS transpose -> line-aligned 8B coalesced stores ----
        #pragma unroll
        for (int ch = 0; ch < 2; ++ch) {
            if (wj == ch) {
                #pragma unroll
                for (int j = 0; j < 4; ++j) {
                    const int c = j * 16 + l16;
                    #pragma unroll
                    for (int i = 0; i < 4; ++i) {
                        const int rloc = wm * 64 + i * 16 + quad * 4;
                        uint2 pp;
                        pp.x = pk2bf(acc[i][j][0], acc[i][j][1]);
                        pp.y = pk2bf(acc[i][j][2], acc[i][j][3]);
                        *(uint2*)&sbuf[c * 136 + rloc] = pp;
                    }
                }
            }
            __syncthreads();
            const int jg = j0 + ch * 64;                 // block-uniform
            uint16_t* const outp = (jg < 512) ? out_v : out_k;
            const int jbase = (jg < 512) ? jg : jg - 512;
            #pragma unroll
            for (int s = 0; s < 8; ++s) {
                const int chunk = tid + 256 * s;         // 2048 chunks
                const int c = chunk >> 5, q = chunk & 31;
                uint2 val = *(const uint2*)&sbuf[c * 136 + q * 4];
                const int r = m0 + q * 4;
                const unsigned bb_ = (unsigned)r / (unsigned)NS;
                const unsigned nn = (unsigned)r - bb_ * (unsigned)NS;
                *(uint2*)&outp[((size_t)bb_ * 512 + jbase + c) * NS + nn] = val;
            }
            __syncthreads();
        }
    }
}

// ---------- fused attention + window means, one block per (b,h), 1024 thr ----------
// Phase 1: BN(k) query, softmax over 961 (thread-per-n), attn kept in LDS,
//          attn integral -> 75 window means (maw) in LDS.
// Phase 2: 64 v-channels, 4 per barrier group, software-pipelined v prefetch:
//          xw = relu(BN(v))*attn, integral, 75 window ratios + center -> y.
__global__ __launch_bounds__(1024, 2)
void k_attnwin(const uint16_t* __restrict__ kraw, const uint16_t* __restrict__ vraw,
               const float* __restrict__ colsum, const float* __restrict__ colsq,
               const float* __restrict__ g_kn, const float* __restrict__ b_kn,
               const float* __restrict__ g_vn, const float* __restrict__ b_vn,
               float* __restrict__ y)
{
    __shared__ float qa[64];
    __shared__ float va[64], vb[64];
    __shared__ float atv[964];        // raw attn weights
    __shared__ float xw[4][964];      // scan workspaces (xw[0] doubles as attn integral)
    __shared__ float maw_s[76];
    __shared__ float red[16];
    __shared__ float s_qb, s_bmax, s_inv;

    const int bh = blockIdx.x;        // b*8 + h
    const int b = bh >> 3, h = bh & 7;
    const int tid = threadIdx.x;      // 1024
    constexpr float invM = 1.f / 61504.f;

    if (tid < 64) {                   // k BN affine + center query
        int c = h * 64 + tid;
        float mean = colsum[512 + c] * invM;
        float q_ = colsq[512 + c] * invM;
        float a = g_kn[c] * rsqrtf(q_ - mean * mean + 1e-5f);
        float bb = b_kn[c] - mean * a;
        float kr = bf2f(kraw[((size_t)b * 512 + c) * NS + 480]);
        float qv = kr * a + bb;
        qa[tid] = qv * a;
        float qb = qv * bb;
        #pragma unroll
        for (int off = 32; off; off >>= 1) qb += __shfl_down(qb, off);
        if (tid == 0) s_qb = qb;
    } else if (tid >= 64 && tid < 128) {   // v BN affine (used in phase 2)
        int t = tid - 64;
        int c = h * 64 + t;
        float mean = colsum[c] * invM;
        float q_ = colsq[c] * invM;
        float a = g_vn[c] * rsqrtf(q_ - mean * mean + 1e-5f);
        va[t] = a;
        vb[t] = b_vn[c] - mean * a;
    }
    __syncthreads();

    // logits: thread-per-n
    float lg = -1e30f;
    if (tid < 961) {
        const uint16_t* kp = kraw + ((size_t)b * 512 + h * 64) * NS + tid;
        float acc = 0.f;
        #pragma unroll 16
        for (int dd = 0; dd < 64; ++dd)
            acc += qa[dd] * bf2f(kp[(size_t)dd * NS]);
        lg = (acc + s_qb) * 0.125f;
    }
    float lmax = lg;
    #pragma unroll
    for (int off = 32; off; off >>= 1) lmax = fmaxf(lmax, __shfl_xor(lmax, off));
    if ((tid & 63) == 0) red[tid >> 6] = lmax;
    __syncthreads();
    if (tid < 64) {
        float v = (tid < 16) ? red[tid] : -1e30f;
        #pragma unroll
        for (int off = 8; off; off >>= 1) v = fmaxf(v, __shfl_xor(v, off));
        if (tid == 0) s_bmax = v;
    }
    __syncthreads();
    float e = (tid < 961) ? __expf(lg - s_bmax) : 0.f;
    float lsum = e;
    #pragma unroll
    for (int off = 32; off; off >>= 1) lsum += __shfl_xor(lsum, off);
    if ((tid & 63) == 0) red[tid >> 6] = lsum;
    __syncthreads();
    if (tid < 64) {
        float v = (tid < 16) ? red[tid] : 0.f;
        #pragma unroll
        for (int off = 8; off; off >>= 1) v += __shfl_xor(v, off);
        if (tid == 0) s_inv = 1.f / v;
    }
    __syncthreads();
    if (tid < 961) {
        float a = e * s_inv;
        atv[tid] = a;
        xw[0][tid] = a;               // integral workspace
    }
    __syncthreads();

    // attn integral (rows then cols), single pass each
    {
        int row = tid >> 5, col = tid & 31;
        bool on = (tid < 992) && (col < 31);
        float v = on ? xw[0][row * 31 + col] : 0.f;
        v = scan32(v, col);
        if (on) xw[0][row * 31 + col] = v;
    }
    __syncthreads();
    {
        int cc = tid >> 5, r = tid & 31;
        bool on = (tid < 992) && (r < 31);
        float v = on ? xw[0][r * 31 + cc] : 0.f;
        v = scan32(v, r);
        if (on) xw[0][r * 31 + cc] = v;
    }
    __syncthreads();
    if (tid < 75) {
        int r0, r1, c0, c1;
        win_idx(tid, r0, r1, c0, c1);
        auto S = [&](int r, int c) -> float { return (r < 0 || c < 0) ? 0.f : xw[0][r * 31 + c]; };
        float box = S(r1 - 1, c1 - 1) - S(r0 - 1, c1 - 1) - S(r1 - 1, c0 - 1) + S(r0 - 1, c0 - 1);
        float cnt = (float)((r1 - r0) * (c1 - c0));
        maw_s[tid] = box / cnt;
    }
    __syncthreads();

    // phase 2: 64 channels, 4 per group, prefetched
    const uint16_t* vbase = vraw + ((size_t)b * 512 + h * 64) * NS + tid;
    float pv[4];
    if (tid < 961) {
        #pragma unroll
        for (int u = 0; u < 4; ++u) pv[u] = bf2f(vbase[(size_t)u * NS]);
    }
    for (int cp = 0; cp < 16; ++cp) {
        if (tid < 961) {
            float myatt = atv[tid];
            #pragma unroll
            for (int u = 0; u < 4; ++u) {
                int cl = cp * 4 + u;
                float w = fmaxf(pv[u] * va[cl] + vb[cl], 0.f) * myatt;
                xw[u][tid] = w;
                if (tid == 480) y[(size_t)b * 76 * 512 + (h * 64 + cl)] = w;  // center row
            }
            if (cp < 15) {
                #pragma unroll
                for (int u = 0; u < 4; ++u) pv[u] = bf2f(vbase[(size_t)(cp * 4 + 4 + u) * NS]);
            }
        }
        __syncthreads();
        {
            int row = tid >> 5, col = tid & 31;
            bool on = (tid < 992) && (col < 31);
            #pragma unroll
            for (int u = 0; u < 4; ++u) {
                float v = on ? xw[u][row * 31 + col] : 0.f;
                v = scan32(v, col);
                if (on) xw[u][row * 31 + col] = v;
            }
        }
        __syncthreads();
        {
            int cc = tid >> 5, r = tid & 31;
            bool on = (tid < 992) && (r < 31);
            #pragma unroll
            for (int u = 0; u < 4; ++u) {
                float v = on ? xw[u][r * 31 + cc] : 0.f;
                v = scan32(v, r);
                if (on) xw[u][r * 31 + cc] = v;
            }
        }
        __syncthreads();
        {
            int u = tid >> 8, w = tid & 255;      // 4 channel-groups of 256 threads
            if (w < 75) {
                int r0, r1, c0, c1;
                win_idx(w, r0, r1, c0, c1);
                auto S = [&](int r, int c) -> float { return (r < 0 || c < 0) ? 0.f : xw[u][r * 31 + c]; };
                float box = S(r1 - 1, c1 - 1) - S(r0 - 1, c1 - 1) - S(r1 - 1, c0 - 1) + S(r0 - 1, c0 - 1);
                float cnt = (float)((r1 - r0) * (c1 - c0));
                float mx = box / cnt;
                int cl = cp * 4 + u;
                y[((size_t)b * 76 + 1 + w) * 512 + (h * 64 + cl)] = mx / (maw_s[w] + 1e-16f);
            }
        }
        __syncthreads();
    }
}

// ---------- row L2-normalize y, build yy = [x0_bf16 | bf16(y/||y||)] ----------
__global__ void k_build_yy(const float* __restrict__ y, const uint16_t* __restrict__ xbt,
                           uint16_t* __restrict__ yy)
{
    __shared__ float red[4];
    int row = blockIdx.x;           // b*76 + r
    int b = row / 76;
    int tid = threadIdx.x;          // 256
    const float* yp = y + (size_t)row * 512;
    float v0 = yp[tid], v1 = yp[tid + 256];
    float ss = v0 * v0 + v1 * v1;
    for (int off = 32; off; off >>= 1) ss += __shfl_xor(ss, off);
    if ((tid & 63) == 0) red[tid >> 6] = ss;
    __syncthreads();
    float tot = red[0] + red[1] + red[2] + red[3];
    float inv = 1.f / fmaxf(sqrtf(tot), 1e-12f);
    uint16_t* op = yy + (size_t)row * 1024;
    const uint16_t* x0p = xbt + ((size_t)b * NS + 480) * 512;
    op[tid]           = x0p[tid];
    op[tid + 256]     = x0p[tid + 256];
    op[512 + tid]       = f2bf(v0 * inv);
    op[512 + tid + 256] = f2bf(v1 * inv);
}

// ---------- final BN + relu (BN affine inline from stats) ----------
__global__ void k_fcout(const float* __restrict__ fcraw,
                        const float* __restrict__ colsum, const float* __restrict__ colsq,
                        const float* __restrict__ g, const float* __restrict__ be,
                        float* __restrict__ out)
{
    size_t idx = (size_t)blockIdx.x * 256 + threadIdx.x;
    if (idx < (size_t)4864 * 512) {
        int j = (int)(idx & 511);
        constexpr float invM = 1.f / 4864.f;
        float mean = colsum[j] * invM;
        float q_ = colsq[j] * invM;
        float a = g[j] * rsqrtf(q_ - mean * mean + 1e-5f);
        float bb = be[j] - mean * a;
        out[idx] = fmaxf(fcraw[idx] * a + bb, 0.f);
    }
}

extern "C" void kernel_launch(void* const* d_in, const int* in_sizes, int n_in,
                              void* d_out, int out_size, void* d_ws, size_t ws_size,
                              hipStream_t stream)
{
    (void)in_sizes; (void)n_in; (void)out_size; (void)ws_size;
    const float* x    = (const float*)d_in[0];
    const float* w_v  = (const float*)d_in[1];
    const float* g_vn = (const float*)d_in[3];
    const float* b_vn = (const float*)d_in[4];
    const float* w_k  = (const float*)d_in[5];
    const float* g_kn = (const float*)d_in[7];
    const float* b_kn = (const float*)d_in[8];
    const float* w_fc = (const float*)d_in[9];
    const float* g_fcn = (const float*)d_in[11];
    const float* b_fcn = (const float*)d_in[12];
    float* out = (float*)d_out;

    char* base = (char*)d_ws;
    size_t off = 0;
    auto alloc = [&](size_t bytes) -> void* {
        void* p = base + off;
        off += (bytes + 255) & ~(size_t)255;
        return p;
    };
    uint16_t* xbt  = (uint16_t*)alloc((size_t)64 * NS * 512 * 2);   // padded rows zeroed
    uint16_t* wvkt = (uint16_t*)alloc((size_t)1024 * 512 * 2);
    uint16_t* wfct = (uint16_t*)alloc((size_t)512 * 1024 * 2);
    uint16_t* vraw = (uint16_t*)alloc((size_t)64 * 512 * NS * 2);
    uint16_t* kraw = (uint16_t*)alloc((size_t)64 * 512 * NS * 2);
    float* stats   = (float*)alloc(3072 * 4);   // vk sum[1024], vk sq[1024], fc sum[512], fc sq[512]
    float* y       = (float*)alloc((size_t)64 * 76 * 512 * 4);
    uint16_t* yy   = (uint16_t*)alloc((size_t)4864 * 1024 * 2);
    float* fcraw   = (float*)alloc((size_t)4864 * 512 * 4);

    hipMemsetAsync(stats, 0, 3072 * 4, stream);
    k_convert_x<<<dim3(31, 16, 64), dim3(32, 8), 0, stream>>>(x, xbt);
    k_convert_w<<<4096, 256, 0, stream>>>(w_v, w_k, w_fc, wvkt, wfct);

    // 62*8*8 = 3968 blocks; (m,j) derived with XCD-affine swizzle (496 m-tiles exact)
    k_gemm<512, 0><<<3968, 256, 0, stream>>>(xbt, wvkt, vraw, kraw, nullptr,
                                             stats, stats + 1024);

    k_attnwin<<<512, 1024, 0, stream>>>(kraw, vraw, stats, stats + 1024,
                                        g_kn, b_kn, g_vn, b_vn, y);
    k_build_yy<<<4864, 256, 0, stream>>>(y, xbt, yy);

    k_gemm<1024, 1><<<dim3(4, 38), 256, 0, stream>>>(yy, wfct, nullptr, nullptr, fcraw,
                                                     stats + 2048, stats + 2560);
    k_fcout<<<9728, 256, 0, stream>>>(fcraw, stats + 2048, stats + 2560, g_fcn, b_fcn, out);
}

// Round 8
// 423.554 us; speedup vs baseline: 1.0925x; 1.0925x over previous
//
#include <hip/hip_runtime.h>
#include <stdint.h>

#define DEV __device__ __forceinline__

typedef __bf16 bf16x8 __attribute__((ext_vector_type(8)));
typedef unsigned short u16x8 __attribute__((ext_vector_type(8)));
typedef uint32_t u32x4 __attribute__((ext_vector_type(4)));
typedef float f32x4 __attribute__((ext_vector_type(4)));

// n-dimension padded stride: 1024 -> row stride 2048 B (line-aligned epilogue
// stores, no RMW), 64*1024 = 512*128 exact tiling, shifts instead of divides.
#define NS 1024

// ---------- bf16 helpers (RNE) ----------
DEV uint16_t f2bf(float f) {
    union { float f; uint32_t u; } v; v.f = f;
    uint32_t r = v.u + 0x7fffu + ((v.u >> 16) & 1u);
    return (uint16_t)(r >> 16);
}
DEV float bf2f(uint16_t h) {
    union { uint32_t u; float f; } v; v.u = ((uint32_t)h) << 16;
    return v.f;
}

#if __has_builtin(__builtin_amdgcn_cvt_pk_bf16_f32)
typedef __bf16 bf16x2 __attribute__((ext_vector_type(2)));
DEV uint32_t pk2bf(float lo, float hi) {
    bf16x2 r = __builtin_amdgcn_cvt_pk_bf16_f32(lo, hi);
    return __builtin_bit_cast(uint32_t, r);
}
#else
DEV uint32_t pk2bf(float lo, float hi) {
    return (uint32_t)f2bf(lo) | ((uint32_t)f2bf(hi) << 16);
}
#endif

// inclusive 32-wide shuffle scan (Hillis-Steele, 5 steps)
DEV float scan32(float v, int lane) {
    #pragma unroll
    for (int d = 1; d < 32; d <<= 1) {
        float o = __shfl_up(v, d, 32);
        if (lane >= d) v += o;
    }
    return v;
}

// window table: w in [0,75) -> r0,r1,c0,c1
DEV void win_idx(int w, int& r0, int& r1, int& c0, int& c1) {
    int i = w / 5 + 1, t = w % 5;
    const int m = 15;
    switch (t) {
        case 0: r0 = m - i; r1 = m + i + 1; c0 = m - i; c1 = m + i + 1; break;
        case 1: r0 = m - i; r1 = m + 1;     c0 = m - i; c1 = m + i + 1; break;
        case 2: r0 = m;     r1 = m + i + 1; c0 = m - i; c1 = m + i + 1; break;
        case 3: r0 = m - i; r1 = m + i + 1; c0 = m - i; c1 = m + 1;     break;
        default:r0 = m - i; r1 = m + i + 1; c0 = m;     c1 = m + i + 1; break;
    }
}

// ---------- async global->LDS, 16B per lane ----------
#if __has_builtin(__builtin_amdgcn_global_load_lds)
DEV void async16(const uint16_t* g, uint16_t* l) {
    __builtin_amdgcn_global_load_lds(
        (const __attribute__((address_space(1))) uint32_t*)g,
        (__attribute__((address_space(3))) uint32_t*)l, 16, 0, 0);
}
#else
DEV void async16(const uint16_t* g, uint16_t* l) {
    *(u16x8*)l = *(const u16x8*)g;
}
#endif

// ---------- transpose + bf16 cast: x (B,512,961) f32 -> xbt (B*1024, 512) bf16 ----------
__global__ void k_convert_x(const float* __restrict__ x, uint16_t* __restrict__ xbt) {
    __shared__ float tile[32][33];
    int b = blockIdx.z;
    int n0 = blockIdx.x * 32;
    int c0 = blockIdx.y * 32;
    int tx = threadIdx.x, ty = threadIdx.y;   // 32 x 8
    #pragma unroll
    for (int i = 0; i < 4; ++i) {
        int c = c0 + ty + 8 * i;
        int n = n0 + tx;
        float v = 0.f;
        if (n < 961) v = x[((size_t)b * 512 + c) * 961 + n];
        tile[ty + 8 * i][tx] = v;
    }
    __syncthreads();
    int idx = ty * 32 + tx;          // 0..255
    int c4 = (idx & 7) * 4;          // 0..28
    int nl = idx >> 3;               // 0..31
    int n = n0 + nl;
    ushort4 val;
    val.x = f2bf(tile[c4 + 0][nl]);
    val.y = f2bf(tile[c4 + 1][nl]);
    val.z = f2bf(tile[c4 + 2][nl]);
    val.w = f2bf(tile[c4 + 3][nl]);
    *(ushort4*)&xbt[((size_t)b * NS + n) * 512 + c0 + c4] = val;
}

// weight converts + window-mask MFMA A-fragments.
__global__ void k_convert_w(const float* __restrict__ wv, const float* __restrict__ wk,
                            const float* __restrict__ wfc,
                            uint16_t* __restrict__ wvkt, uint16_t* __restrict__ wfct,
                            uint16_t* __restrict__ wfrag) {
    int idx = blockIdx.x * 256 + threadIdx.x;   // 0 .. 1130495
    if (idx < 524288) {
        int j = idx >> 9, k = idx & 511;
        float v = (j < 512) ? wv[(size_t)k * 512 + j] : wk[(size_t)k * 512 + (j - 512)];
        wvkt[idx] = f2bf(v);
    } else if (idx < 1048576) {
        int t = idx - 524288;
        int j = t >> 10, k = t & 1023;
        wfct[t] = f2bf(wfc[(size_t)k * 512 + j]);
    } else {
        int t = idx - 1048576;        // [0, 81920)
        int e = t & 7;
        int lane = (t >> 3) & 63;
        int kt = (t >> 9) & 31;
        int mt = t >> 14;             // 0..4
        int m = mt * 16 + (lane & 15);
        int k = kt * 32 + (lane >> 4) * 8 + e;
        uint16_t out = 0;
        if (m < 75 && k < 961) {
            int r = k / 31, cc = k - r * 31;
            int r0, r1, c0, c1;
            win_idx(m, r0, r1, c0, c1);
            if (r >= r0 && r < r1 && cc >= c0 && cc < c1) out = 0x3f80;  // bf16 1.0
        }
        wfrag[t] = out;
    }
}

// ---------- bf16 MFMA GEMM, 128x128 tile, BK=64 (two 32-k panels) ----------
template<int K, int EPI>
__global__ __launch_bounds__(256, 4)
void k_gemm(const uint16_t* __restrict__ A, const uint16_t* __restrict__ Bt,
            uint16_t* __restrict__ out_v, uint16_t* __restrict__ out_k,
            float* __restrict__ out_f,
            float* __restrict__ colsum, float* __restrict__ colsq)
{
    __shared__ __align__(16) uint16_t sbuf[16384];   // 32 KB staging / epi-transpose
    __shared__ float sStat[256];
    uint16_t* sA0 = sbuf;
    uint16_t* sA1 = sbuf + 4096;
    uint16_t* sB0 = sbuf + 8192;
    uint16_t* sB1 = sbuf + 12288;

    const int tid = threadIdx.x;
    const int wave = tid >> 6, lane = tid & 63;
    const int quad = lane >> 4, l16 = lane & 15;
    int m0, j0;
    if constexpr (EPI == 0) {
        int lin = blockIdx.x;            // 64*8*8 = 4096, 512 m-tiles exact
        int xcd = lin & 7, rest = lin >> 3;
        int jb = rest & 7, mhi = rest >> 3;
        m0 = (mhi * 8 + xcd) * 128; j0 = jb * 128;
    } else {
        m0 = blockIdx.y * 128; j0 = blockIdx.x * 128;
    }
    const int wm = wave >> 1, wj = wave & 1;

    const f32x4 fzero = {0.f, 0.f, 0.f, 0.f};
    f32x4 acc[4][4];
    #pragma unroll
    for (int i = 0; i < 4; ++i)
        #pragma unroll
        for (int j = 0; j < 4; ++j) acc[i][j] = fzero;

    const int c0 = tid;
    const int mA0 = c0 >> 2, kq0 = c0 & 3;
    const int c1 = tid + 256;
    const int mA1 = c1 >> 2, kq1 = c1 & 3;

    const int KT = K / 64;
    for (int kt = 0; kt < KT; ++kt) {
        const uint16_t* Ak = A + (size_t)m0 * K + kt * 64;
        const uint16_t* Bk = Bt + (size_t)j0 * K + kt * 64;
        async16(Ak + (size_t)mA0 * K + kq0 * 8,      &sA0[c0 * 8]);
        async16(Ak + (size_t)mA1 * K + kq1 * 8,      &sA0[c1 * 8]);
        async16(Ak + (size_t)mA0 * K + 32 + kq0 * 8, &sA1[c0 * 8]);
        async16(Ak + (size_t)mA1 * K + 32 + kq1 * 8, &sA1[c1 * 8]);
        async16(Bk + (size_t)mA0 * K + kq0 * 8,      &sB0[c0 * 8]);
        async16(Bk + (size_t)mA1 * K + kq1 * 8,      &sB0[c1 * 8]);
        async16(Bk + (size_t)mA0 * K + 32 + kq0 * 8, &sB1[c0 * 8]);
        async16(Bk + (size_t)mA1 * K + 32 + kq1 * 8, &sB1[c1 * 8]);
        __syncthreads();
        #pragma unroll
        for (int p = 0; p < 2; ++p) {
            const uint16_t* pA = p ? sA1 : sA0;
            const uint16_t* pB = p ? sB1 : sB0;
            bf16x8 af[4], bfr[4];
            #pragma unroll
            for (int i = 0; i < 4; ++i) {
                int m = wm * 64 + i * 16 + l16;
                u16x8 r = *(const u16x8*)&pA[m * 32 + quad * 8];
                af[i] = __builtin_bit_cast(bf16x8, r);
            }
            #pragma unroll
            for (int j = 0; j < 4; ++j) {
                int jj = wj * 64 + j * 16 + l16;
                u16x8 r = *(const u16x8*)&pB[jj * 32 + quad * 8];
                bfr[j] = __builtin_bit_cast(bf16x8, r);
            }
            #pragma unroll
            for (int i = 0; i < 4; ++i)
                #pragma unroll
                for (int j = 0; j < 4; ++j)
                    acc[i][j] = __builtin_amdgcn_mfma_f32_16x16x32_bf16(af[i], bfr[j], acc[i][j], 0, 0, 0);
        }
        __syncthreads();
    }

    // ---- column stats (pad rows exactly zero -> unconditional) ----
    sStat[tid] = 0.f;
    __syncthreads();

    #pragma unroll
    for (int j = 0; j < 4; ++j) {
        const int col_local = wj * 64 + j * 16 + l16;
        float ls = 0.f, lq = 0.f;
        #pragma unroll
        for (int i = 0; i < 4; ++i) {
            #pragma unroll
            for (int reg = 0; reg < 4; ++reg) {
                const float val = acc[i][j][reg];
                ls += val; lq += val * val;
                if constexpr (EPI == 1) {
                    const int r = m0 + wm * 64 + i * 16 + quad * 4 + reg;
                    out_f[(size_t)r * 512 + (j0 + col_local)] = val;
                }
            }
        }
        ls += __shfl_xor(ls, 16); lq += __shfl_xor(lq, 16);
        ls += __shfl_xor(ls, 32); lq += __shfl_xor(lq, 32);
        if (quad == 0) {
            atomicAdd(&sStat[col_local], ls);
            atomicAdd(&sStat[128 + col_local], lq);
        }
    }
    __syncthreads();
    if (tid < 128) atomicAdd(&colsum[j0 + tid], sStat[tid]);
    else           atomicAdd(&colsq[j0 + (tid & 127)], sStat[tid]);

    if constexpr (EPI == 0) {
        // ---- LDS transpose -> 256B-aligned 8B coalesced stores (no RMW) ----
        #pragma unroll
        for (int ch = 0; ch < 2; ++ch) {
            if (wj == ch) {
                #pragma unroll
                for (int j = 0; j < 4; ++j) {
                    const int c = j * 16 + l16;
                    #pragma unroll
                    for (int i = 0; i < 4; ++i) {
                        const int rloc = wm * 64 + i * 16 + quad * 4;
                        uint2 pp;
                        pp.x = pk2bf(acc[i][j][0], acc[i][j][1]);
                        pp.y = pk2bf(acc[i][j][2], acc[i][j][3]);
                        *(uint2*)&sbuf[c * 136 + rloc] = pp;
                    }
                }
            }
            __syncthreads();
            const int jg = j0 + ch * 64;                 // block-uniform
            uint16_t* const outp = (jg < 512) ? out_v : out_k;
            const int jbase = (jg < 512) ? jg : jg - 512;
            #pragma unroll
            for (int s = 0; s < 8; ++s) {
                const int chunk = tid + 256 * s;         // 2048 chunks
                const int c = chunk >> 5, q = chunk & 31;
                uint2 val = *(const uint2*)&sbuf[c * 136 + q * 4];
                const int r = m0 + q * 4;
                const unsigned bb_ = (unsigned)r >> 10;
                const unsigned nn = (unsigned)r & 1023u;
                *(uint2*)&outp[((size_t)bb_ * 512 + jbase + c) * NS + nn] = val;
            }
            __syncthreads();
        }
    }
}

// ---------- fused attention + window means, one block per (b,h), 256 thr ----------
// Phase 1: BN(k) query, softmax over 961 (4 n/thread), attn -> LDS (fp32 + bf16),
//          attn integral (scan32) -> 75 window means maw in LDS.
// Phase 2: window box-sums as mask GEMM: C(80x64) = Wmask(80x992) @ xw(992x64),
//          xw B-fragments built in registers from 16B v loads; Wmask A-frags
//          precomputed in global (L2-resident). 5 MFMA per wave per k-tile.
__global__ __launch_bounds__(256, 4)
void k_attnwin(const uint16_t* __restrict__ kraw, const uint16_t* __restrict__ vraw,
               const uint16_t* __restrict__ wfrag,
               const float* __restrict__ colsum, const float* __restrict__ colsq,
               const float* __restrict__ g_kn, const float* __restrict__ b_kn,
               const float* __restrict__ g_vn, const float* __restrict__ b_vn,
               float* __restrict__ y)
{
    __shared__ float qa[64];
    __shared__ float va[64], vb[64];
    __shared__ float atv[992];         // fp32 attn, then integral (in place)
    __shared__ __align__(16) uint16_t attb[1024];  // bf16 attn, pad zeroed
    __shared__ float maw_s[80];
    __shared__ float cnt_s[80];
    __shared__ float red[4];
    __shared__ float s_qb, s_bmax, s_inv;

    const int bh = blockIdx.x;        // b*8 + h
    const int b = bh >> 3, h = bh & 7;
    const int tid = threadIdx.x;      // 256
    const int lane = tid & 63, wave = tid >> 6;
    const int quad = lane >> 4, l16 = lane & 15;
    constexpr float invM = 1.f / 61504.f;

    if (tid < 64) {                   // k BN affine + center query
        int c = h * 64 + tid;
        float mean = colsum[512 + c] * invM;
        float q_ = colsq[512 + c] * invM;
        float a = g_kn[c] * rsqrtf(q_ - mean * mean + 1e-5f);
        float bb = b_kn[c] - mean * a;
        float kr = bf2f(kraw[((size_t)b * 512 + c) * NS + 480]);
        float qv = kr * a + bb;
        qa[tid] = qv * a;
        float qb = qv * bb;
        #pragma unroll
        for (int off = 32; off; off >>= 1) qb += __shfl_down(qb, off);
        if (tid == 0) s_qb = qb;
    } else if (tid < 128) {           // v BN affine
        int t = tid - 64;
        int c = h * 64 + t;
        float mean = colsum[c] * invM;
        float q_ = colsq[c] * invM;
        float a = g_vn[c] * rsqrtf(q_ - mean * mean + 1e-5f);
        va[t] = a;
        vb[t] = b_vn[c] - mean * a;
    }
    __syncthreads();

    // logits: 4 n per thread
    const int n4 = tid * 4;
    float lg[4];
    float lmax = -1e30f;
    {
        const uint16_t* kp = kraw + ((size_t)b * 512 + h * 64) * NS + n4;
        float a0 = 0.f, a1 = 0.f, a2 = 0.f, a3 = 0.f;
        if (n4 < 961) {
            #pragma unroll 16
            for (int dd = 0; dd < 64; ++dd) {
                uint2 kk = *(const uint2*)(kp + (size_t)dd * NS);
                u16x8 kk4 = {};
                kk4[0] = (uint16_t)(kk.x & 0xffffu);
                kk4[1] = (uint16_t)(kk.x >> 16);
                kk4[2] = (uint16_t)(kk.y & 0xffffu);
                kk4[3] = (uint16_t)(kk.y >> 16);
                float q = qa[dd];
                a0 += q * bf2f(kk4[0]);
                a1 += q * bf2f(kk4[1]);
                a2 += q * bf2f(kk4[2]);
                a3 += q * bf2f(kk4[3]);
            }
        }
        lg[0] = a0; lg[1] = a1; lg[2] = a2; lg[3] = a3;
        #pragma unroll
        for (int i = 0; i < 4; ++i) {
            lg[i] = (lg[i] + s_qb) * 0.125f;
            if (n4 + i < 961) lmax = fmaxf(lmax, lg[i]);
        }
    }
    #pragma unroll
    for (int off = 32; off; off >>= 1) lmax = fmaxf(lmax, __shfl_xor(lmax, off));
    if (lane == 0) red[wave] = lmax;
    __syncthreads();
    if (tid == 0) s_bmax = fmaxf(fmaxf(red[0], red[1]), fmaxf(red[2], red[3]));
    __syncthreads();
    float lsum = 0.f;
    #pragma unroll
    for (int i = 0; i < 4; ++i) {
        float e = (n4 + i < 961) ? __expf(lg[i] - s_bmax) : 0.f;
        lg[i] = e;
        lsum += e;
    }
    #pragma unroll
    for (int off = 32; off; off >>= 1) lsum += __shfl_xor(lsum, off);
    if (lane == 0) red[wave] = lsum;
    __syncthreads();
    if (tid == 0) s_inv = 1.f / (red[0] + red[1] + red[2] + red[3]);
    __syncthreads();
    {
        uint2 pk;
        float w0 = (n4 + 0 < 961) ? lg[0] * s_inv : 0.f;
        float w1 = (n4 + 1 < 961) ? lg[1] * s_inv : 0.f;
        float w2 = (n4 + 2 < 961) ? lg[2] * s_inv : 0.f;
        float w3 = (n4 + 3 < 961) ? lg[3] * s_inv : 0.f;
        pk.x = pk2bf(w0, w1);
        pk.y = pk2bf(w2, w3);
        *(uint2*)&attb[n4] = pk;
        #pragma unroll
        for (int i = 0; i < 4; ++i)
            if (n4 + i < 961) atv[n4 + i] = lg[i] * s_inv;
    }
    __syncthreads();

    // center output row (reads atv before integral overwrites it)
    if (tid < 64) {
        float vv = bf2f(vraw[((size_t)(b * 512 + h * 64 + tid)) * NS + 480]);
        y[(size_t)b * 76 * 512 + h * 64 + tid] = fmaxf(vv * va[tid] + vb[tid], 0.f) * atv[480];
    }
    __syncthreads();

    // attn integral (rows then cols)
    {
        int col = tid & 31, r8 = tid >> 5;
        #pragma unroll
        for (int p = 0; p < 4; ++p) {
            int row = p * 8 + r8;
            bool on = (row < 31) && (col < 31);
            float v = on ? atv[row * 31 + col] : 0.f;
            v = scan32(v, col);
            if (on) atv[row * 31 + col] = v;
        }
    }
    __syncthreads();
    {
        int r = tid & 31, c8 = tid >> 5;
        #pragma unroll
        for (int p = 0; p < 4; ++p) {
            int cc = p * 8 + c8;
            bool on = (cc < 31) && (r < 31);
            float v = on ? atv[r * 31 + cc] : 0.f;
            v = scan32(v, r);
            if (on) atv[r * 31 + cc] = v;
        }
    }
    __syncthreads();
    if (tid < 75) {
        int r0, r1, c0, c1;
        win_idx(tid, r0, r1, c0, c1);
        auto S = [&](int r, int c) -> float { return (r < 0 || c < 0) ? 0.f : atv[r * 31 + c]; };
        float box = S(r1 - 1, c1 - 1) - S(r0 - 1, c1 - 1) - S(r1 - 1, c0 - 1) + S(r0 - 1, c0 - 1);
        float cnt = (float)((r1 - r0) * (c1 - c0));
        cnt_s[tid] = cnt;
        maw_s[tid] = box / cnt;
    }
    __syncthreads();

    // phase 2: mask GEMM. wave -> 16 channels; 5 m-tiles; 31 k-tiles.
    {
        const int cl = wave * 16 + l16;          // channel local 0..63
        const float a_bn = va[cl], b_bn = vb[cl];
        const uint16_t* vp = vraw + ((size_t)(b * 512 + h * 64 + cl)) * NS + quad * 8;
        f32x4 acc5[5];
        const f32x4 fz = {0.f, 0.f, 0.f, 0.f};
        #pragma unroll
        for (int mt = 0; mt < 5; ++mt) acc5[mt] = fz;
        for (int kt = 0; kt < 31; ++kt) {
            u16x8 vv = *(const u16x8*)(vp + kt * 32);
            u16x8 aa = *(const u16x8*)&attb[kt * 32 + quad * 8];
            u32x4 bwu;
            #pragma unroll
            for (int e = 0; e < 4; ++e) {
                float x0 = fmaxf(bf2f(vv[2 * e]) * a_bn + b_bn, 0.f) * bf2f(aa[2 * e]);
                float x1 = fmaxf(bf2f(vv[2 * e + 1]) * a_bn + b_bn, 0.f) * bf2f(aa[2 * e + 1]);
                bwu[e] = pk2bf(x0, x1);
            }
            bf16x8 bfr = __builtin_bit_cast(bf16x8, bwu);
            #pragma unroll
            for (int mt = 0; mt < 5; ++mt) {
                u16x8 wf = *(const u16x8*)&wfrag[(((mt * 32 + kt) * 64 + lane)) * 8];
                acc5[mt] = __builtin_amdgcn_mfma_f32_16x16x32_bf16(
                    __builtin_bit_cast(bf16x8, wf), bfr, acc5[mt], 0, 0, 0);
            }
        }
        // epilogue: C row (M side) = w = mt*16 + quad*4 + reg; col (N side) = cl
        const int cg = h * 64 + cl;
        #pragma unroll
        for (int mt = 0; mt < 5; ++mt) {
            #pragma unroll
            for (int reg = 0; reg < 4; ++reg) {
                int w = mt * 16 + quad * 4 + reg;
                if (w < 75) {
                    float mx = acc5[mt][reg] / cnt_s[w];
                    y[((size_t)b * 76 + 1 + w) * 512 + cg] = mx / (maw_s[w] + 1e-16f);
                }
            }
        }
    }
}

// ---------- row L2-normalize y, build yy = [x0_bf16 | bf16(y/||y||)] ----------
__global__ void k_build_yy(const float* __restrict__ y, const uint16_t* __restrict__ xbt,
                           uint16_t* __restrict__ yy)
{
    __shared__ float red[4];
    int row = blockIdx.x;           // b*76 + r
    int b = row / 76;
    int tid = threadIdx.x;          // 256
    const float* yp = y + (size_t)row * 512;
    float v0 = yp[tid], v1 = yp[tid + 256];
    float ss = v0 * v0 + v1 * v1;
    for (int off = 32; off; off >>= 1) ss += __shfl_xor(ss, off);
    if ((tid & 63) == 0) red[tid >> 6] = ss;
    __syncthreads();
    float tot = red[0] + red[1] + red[2] + red[3];
    float inv = 1.f / fmaxf(sqrtf(tot), 1e-12f);
    uint16_t* op = yy + (size_t)row * 1024;
    const uint16_t* x0p = xbt + ((size_t)b * NS + 480) * 512;
    op[tid]           = x0p[tid];
    op[tid + 256]     = x0p[tid + 256];
    op[512 + tid]       = f2bf(v0 * inv);
    op[512 + tid + 256] = f2bf(v1 * inv);
}

// ---------- final BN + relu (BN affine inline from stats) ----------
__global__ void k_fcout(const float* __restrict__ fcraw,
                        const float* __restrict__ colsum, const float* __restrict__ colsq,
                        const float* __restrict__ g, const float* __restrict__ be,
                        float* __restrict__ out)
{
    size_t idx = (size_t)blockIdx.x * 256 + threadIdx.x;
    if (idx < (size_t)4864 * 512) {
        int j = (int)(idx & 511);
        constexpr float invM = 1.f / 4864.f;
        float mean = colsum[j] * invM;
        float q_ = colsq[j] * invM;
        float a = g[j] * rsqrtf(q_ - mean * mean + 1e-5f);
        float bb = be[j] - mean * a;
        out[idx] = fmaxf(fcraw[idx] * a + bb, 0.f);
    }
}

extern "C" void kernel_launch(void* const* d_in, const int* in_sizes, int n_in,
                              void* d_out, int out_size, void* d_ws, size_t ws_size,
                              hipStream_t stream)
{
    (void)in_sizes; (void)n_in; (void)out_size; (void)ws_size;
    const float* x    = (const float*)d_in[0];
    const float* w_v  = (const float*)d_in[1];
    const float* g_vn = (const float*)d_in[3];
    const float* b_vn = (const float*)d_in[4];
    const float* w_k  = (const float*)d_in[5];
    const float* g_kn = (const float*)d_in[7];
    const float* b_kn = (const float*)d_in[8];
    const float* w_fc = (const float*)d_in[9];
    const float* g_fcn = (const float*)d_in[11];
    const float* b_fcn = (const float*)d_in[12];
    float* out = (float*)d_out;

    char* base = (char*)d_ws;
    size_t off = 0;
    auto alloc = [&](size_t bytes) -> void* {
        void* p = base + off;
        off += (bytes + 255) & ~(size_t)255;
        return p;
    };
    uint16_t* xbt  = (uint16_t*)alloc((size_t)64 * NS * 512 * 2);   // pad rows zeroed
    uint16_t* wvkt = (uint16_t*)alloc((size_t)1024 * 512 * 2);
    uint16_t* wfct = (uint16_t*)alloc((size_t)512 * 1024 * 2);
    uint16_t* wfrag = (uint16_t*)alloc((size_t)5 * 32 * 64 * 8 * 2);  // 160 KB mask frags
    uint16_t* vraw = (uint16_t*)alloc((size_t)64 * 512 * NS * 2);
    uint16_t* kraw = (uint16_t*)alloc((size_t)64 * 512 * NS * 2);
    float* stats   = (float*)alloc(3072 * 4);
    float* y       = (float*)alloc((size_t)64 * 76 * 512 * 4);
    uint16_t* yy   = (uint16_t*)alloc((size_t)4864 * 1024 * 2);
    float* fcraw   = (float*)alloc((size_t)4864 * 512 * 4);

    hipMemsetAsync(stats, 0, 3072 * 4, stream);
    k_convert_x<<<dim3(32, 16, 64), dim3(32, 8), 0, stream>>>(x, xbt);
    k_convert_w<<<4416, 256, 0, stream>>>(w_v, w_k, w_fc, wvkt, wfct, wfrag);

    // 64*8*8 = 4096 blocks; (m,j) via XCD-affine swizzle (512 m-tiles exact)
    k_gemm<512, 0><<<4096, 256, 0, stream>>>(xbt, wvkt, vraw, kraw, nullptr,
                                             stats, stats + 1024);

    k_attnwin<<<512, 256, 0, stream>>>(kraw, vraw, wfrag, stats, stats + 1024,
                                       g_kn, b_kn, g_vn, b_vn, y);
    k_build_yy<<<4864, 256, 0, stream>>>(y, xbt, yy);

    k_gemm<1024, 1><<<dim3(4, 38), 256, 0, stream>>>(yy, wfct, nullptr, nullptr, fcraw,
                                                     stats + 2048, stats + 2560);
    k_fcout<<<9728, 256, 0, stream>>>(fcraw, stats + 2048, stats + 2560, g_fcn, b_fcn, out);
}